// Round 3
// baseline (295.745 us; speedup 1.0000x reference)
//
#include <hip/hip_runtime.h>
#include <hip/hip_bf16.h>
#include <math.h>

// Problem constants
#define BATCH 1024
#define NREAL 784
#define NPAD  896      // 7*128, zero-padded graph dim
#define C1D   32
#define C2D   32
#define HDIM  512
#define NCLS  10
#define KFC   25088    // 784*32

#define KS_G1 7        // split-K for G1 (K=896 -> 128/slice, 4 iters, EVEN)
#define KS_FC 14       // split-K for fc1 (K=25088 -> 1792/slice, 56 iters, EVEN)

// GEMM tile (128x128 kernel, used for G1/G4)
#define BM 128
#define BN 128
#define BK 32

using bf16x8  = __attribute__((ext_vector_type(8))) __bf16;
using floatx4 = __attribute__((ext_vector_type(4))) float;

__device__ __forceinline__ float elu_f(float t) {
    return t > 0.f ? t : (__expf(t) - 1.f);
}

// LDS-only barrier: waits ds ops but leaves global loads (vmcnt) in flight.
__device__ __forceinline__ void wg_barrier_lds() {
    asm volatile("s_waitcnt lgkmcnt(0)\n\ts_barrier" ::: "memory");
}

// raw barrier (no waitcnt)
__device__ __forceinline__ void bar() {
    asm volatile("s_barrier" ::: "memory");
}

// async global->LDS, 16B per lane; LDS dest is wave-uniform base + lane*16
__device__ __forceinline__ void gload_lds16(const __hip_bfloat16* g, __hip_bfloat16* l) {
    __builtin_amdgcn_global_load_lds(
        (const __attribute__((address_space(1))) void*)g,
        (__attribute__((address_space(3))) void*)l, 16, 0, 0);
}

// ---------------------------------------------------------------------------
// BT-GEMM, register-staged pipeline + XOR-swizzled LDS layout (G1, G4).
// (unchanged)
// ---------------------------------------------------------------------------
template<int MODE>
__launch_bounds__(256)
__global__ void gemm_bt(const __hip_bfloat16* __restrict__ A, int lda,
                        const __hip_bfloat16* __restrict__ Bm, int ldb,
                        int kIters, int kPerZ, size_t sliceStride,
                        float* __restrict__ outF, int ldc,
                        __hip_bfloat16* __restrict__ outH,
                        const float* __restrict__ bias)
{
    __shared__ __align__(16) __hip_bfloat16 As[2][BM * BK];
    __shared__ __align__(16) __hip_bfloat16 Bs[2][BN * BK];

    const int tid  = threadIdx.x;
    const int lane = tid & 63;
    const int wave = tid >> 6;
    const int wi = wave >> 1, wj = wave & 1;

    const int m0 = blockIdx.y * BM;
    const int n0 = blockIdx.x * BN;
    const int kBase = blockIdx.z * kPerZ;

    const int rowInChunk = lane >> 2;
    const int kOff8 = (lane & 3) * 8;

    const __hip_bfloat16* aSrc0 = A  + (size_t)(m0 + (wave * 2 + 0) * 16 + rowInChunk) * lda + kBase + kOff8;
    const __hip_bfloat16* aSrc1 = A  + (size_t)(m0 + (wave * 2 + 1) * 16 + rowInChunk) * lda + kBase + kOff8;
    const __hip_bfloat16* bSrc0 = Bm + (size_t)(n0 + (wave * 2 + 0) * 16 + rowInChunk) * ldb + kBase + kOff8;
    const __hip_bfloat16* bSrc1 = Bm + (size_t)(n0 + (wave * 2 + 1) * 16 + rowInChunk) * ldb + kBase + kOff8;

    const int wSlot = (((lane & 3) + ((lane >> 3) & 3)) & 3) * 8;
    const int ldsW0 = (wave * 2 + 0) * 512 + rowInChunk * 32 + wSlot;
    const int ldsW1 = ldsW0 + 512;

    const int rSlot = ((((lane >> 4) + (((lane & 15) >> 1) & 3)) & 3)) * 8;
    const int rRow  = lane & 15;

    floatx4 acc[4][4];
    const floatx4 zero4 = {0.f, 0.f, 0.f, 0.f};
    #pragma unroll
    for (int i = 0; i < 4; i++)
        #pragma unroll
        for (int j = 0; j < 4; j++) acc[i][j] = zero4;

    int4 aA0, aA1, bA0, bA1;
    int4 aB0, aB1, bB0, bB1;

    aA0 = *(const int4*)aSrc0; aA1 = *(const int4*)aSrc1;
    bA0 = *(const int4*)bSrc0; bA1 = *(const int4*)bSrc1;
    aSrc0 += BK; aSrc1 += BK; bSrc0 += BK; bSrc1 += BK;
    aB0 = *(const int4*)aSrc0; aB1 = *(const int4*)aSrc1;
    bB0 = *(const int4*)bSrc0; bB1 = *(const int4*)bSrc1;
    aSrc0 += BK; aSrc1 += BK; bSrc0 += BK; bSrc1 += BK;

    *(int4*)(&As[0][ldsW0]) = aA0;
    *(int4*)(&As[0][ldsW1]) = aA1;
    *(int4*)(&Bs[0][ldsW0]) = bA0;
    *(int4*)(&Bs[0][ldsW1]) = bA1;
    wg_barrier_lds();

    for (int kt = 0; kt < kIters; kt += 2) {
        const bool more = (kt + 2 < kIters);

        {
            bf16x8 af[4], bfr[4];
            #pragma unroll
            for (int mi = 0; mi < 4; mi++)
                af[mi] = *(const bf16x8*)(&As[0][(wi * 64 + mi * 16 + rRow) * BK + rSlot]);
            #pragma unroll
            for (int nj = 0; nj < 4; nj++)
                bfr[nj] = *(const bf16x8*)(&Bs[0][(wj * 64 + nj * 16 + rRow) * BK + rSlot]);

            if (more) {
                aA0 = *(const int4*)aSrc0; aA1 = *(const int4*)aSrc1;
                bA0 = *(const int4*)bSrc0; bA1 = *(const int4*)bSrc1;
                aSrc0 += BK; aSrc1 += BK; bSrc0 += BK; bSrc1 += BK;
            }
            *(int4*)(&As[1][ldsW0]) = aB0;
            *(int4*)(&As[1][ldsW1]) = aB1;
            *(int4*)(&Bs[1][ldsW0]) = bB0;
            *(int4*)(&Bs[1][ldsW1]) = bB1;

            #pragma unroll
            for (int mi = 0; mi < 4; mi++)
                #pragma unroll
                for (int nj = 0; nj < 4; nj++)
                    acc[mi][nj] = __builtin_amdgcn_mfma_f32_16x16x32_bf16(af[mi], bfr[nj], acc[mi][nj], 0, 0, 0);

            wg_barrier_lds();
        }

        {
            bf16x8 af[4], bfr[4];
            #pragma unroll
            for (int mi = 0; mi < 4; mi++)
                af[mi] = *(const bf16x8*)(&As[1][(wi * 64 + mi * 16 + rRow) * BK + rSlot]);
            #pragma unroll
            for (int nj = 0; nj < 4; nj++)
                bfr[nj] = *(const bf16x8*)(&Bs[1][(wj * 64 + nj * 16 + rRow) * BK + rSlot]);

            if (more) {
                aB0 = *(const int4*)aSrc0; aB1 = *(const int4*)aSrc1;
                bB0 = *(const int4*)bSrc0; bB1 = *(const int4*)bSrc1;
                aSrc0 += BK; aSrc1 += BK; bSrc0 += BK; bSrc1 += BK;
                *(int4*)(&As[0][ldsW0]) = aA0;
                *(int4*)(&As[0][ldsW1]) = aA1;
                *(int4*)(&Bs[0][ldsW0]) = bA0;
                *(int4*)(&Bs[0][ldsW1]) = bA1;
            }

            #pragma unroll
            for (int mi = 0; mi < 4; mi++)
                #pragma unroll
                for (int nj = 0; nj < 4; nj++)
                    acc[mi][nj] = __builtin_amdgcn_mfma_f32_16x16x32_bf16(af[mi], bfr[nj], acc[mi][nj], 0, 0, 0);

            wg_barrier_lds();
        }
    }

    #pragma unroll
    for (int mi = 0; mi < 4; mi++) {
        #pragma unroll
        for (int nj = 0; nj < 4; nj++) {
            #pragma unroll
            for (int r = 0; r < 4; r++) {
                const int row = m0 + wi * 64 + mi * 16 + (lane >> 4) * 4 + r;
                const int col = n0 + wj * 64 + nj * 16 + (lane & 15);
                const float v = acc[mi][nj][r];
                if (MODE == 1) {
                    if (row < NREAL) {
                        const int c = col & 31, b = col >> 5;
                        const float t = elu_f(v + bias[c]);
                        outH[(size_t)b * KFC + row * 32 + c] = __float2bfloat16(t);
                    }
                } else {
                    outF[(size_t)blockIdx.z * sliceStride + (size_t)row * ldc + col] = v;
                }
            }
        }
    }
}

// ---------------------------------------------------------------------------
// G3: 256x256 GEMM, per-wave-owned output + half-slot ring pipeline.
//
//   C[n][j] = sum_m Abf[n][m] * Tt[j][m].  K = 896 = 14 tiles of BK=64.
//
// 8 waves (2M x 4N).  Wave (vm,vn) OWNS C-block rows vm*128..+128, cols
// vn*64..+64: reads ONLY A-half vm and B-half vn>>1.  Per tile per wave:
// A read once (16 ds_read_b128), B k-halves held in regs across mh-phases
// (8 reads) -> 24 KB/wave/tile (round-2 quadrant scheme: 48 KB — LDS read
// traffic was the critical path, MfmaUtil 31%).
//
// LDS: ring of 4 half-slots per matrix (slot = (2t+h)&3, 128 KiB total).
// Rotation swizzle within rows (slot(k>>3) = (k>>3 + row&7)&7): reads
// 2-way-free; staging = linear LDS dest + pre-swizzled global src (#21).
//
// Sync: ONE vmcnt(0)+barrier per tile boundary.  Ledger:
//   - stages for t+1 issued at t.p0 (A) / t.p1 (B) target slots (2t+2+h)&3,
//     last read in tile t-1, all waves past boundary-t barrier -> safe.
//   - tile-t loads issued 4 phases (~1 tile) earlier -> vmcnt(0) is cheap.
//   - within a tile waves free-run (no inter-phase barriers; each wave
//     reads only its own halves) -> real role-split for s_setprio.
// 4 phases/tile (kh,mh), 16 MFMA each; compiler schedules ds_reads/lgkmcnt.
// ---------------------------------------------------------------------------
#define KT_G3 14

#define STAGE_A(tt, hh) do {                                                    \
    const int s_ = (2 * (tt) + (hh)) & 3;                                       \
    gload_lds16(aSrcH[hh][0] + (tt) * 64, &Ah[s_][(wave * 2 + 0) * 512]);       \
    gload_lds16(aSrcH[hh][1] + (tt) * 64, &Ah[s_][(wave * 2 + 1) * 512]);       \
} while (0)

#define STAGE_B(tt, hh) do {                                                    \
    const int s_ = (2 * (tt) + (hh)) & 3;                                       \
    gload_lds16(bSrcH[hh][0] + (tt) * 64, &Bh[s_][(wave * 2 + 0) * 512]);       \
    gload_lds16(bSrcH[hh][1] + (tt) * 64, &Bh[s_][(wave * 2 + 1) * 512]);       \
} while (0)

__launch_bounds__(512, 2)
__global__ void gemm256_g3(const __hip_bfloat16* __restrict__ Ag,   // Abf [896][896]
                           const __hip_bfloat16* __restrict__ Bg,   // Tt  [32768][896]
                           __hip_bfloat16* __restrict__ outH,       // h2f
                           const float* __restrict__ bias)          // b2 [32]
{
    __shared__ __align__(16) __hip_bfloat16 Ah[4][128 * 64];
    __shared__ __align__(16) __hip_bfloat16 Bh[4][128 * 64];

    const int tid  = threadIdx.x;
    const int lane = tid & 63;
    const int wave = tid >> 6;
    const int vm = wave >> 2, vn = wave & 3;
    const int hbB = vn >> 1;                 // B-half this wave reads

    const int mR = blockIdx.y * 256;    // output rows (Abf rows; >=896 clamped+masked)
    const int nR = blockIdx.x * 256;    // output cols (Tt rows)

    // ---- read-side constants ----
    const int rRow = lane & 15;
    const int gHi  = lane >> 4;              // 0..3 (k-group within half-K)
    const int rot  = lane & 7;               // == (read row) & 7
    const int koff0 = (((gHi + rot) & 7) << 3);
    const int koff1 = ((((gHi + 4) + rot) & 7) << 3);
    const int aRow0 = rRow * 64;                       // + mi*1024
    const int bRow0 = ((vn & 1) * 64 + rRow) * 64;     // + nj*1024

    // ---- staging constants (pre-swizzled global source, linear LDS dest) ----
    const int rowLoc = lane >> 3;                       // row within 8-row chunk
    const int gOff   = ((((lane & 7) - rowLoc) & 7) << 3);
    const __hip_bfloat16* aSrcH[2][2];
    const __hip_bfloat16* bSrcH[2][2];
    #pragma unroll
    for (int h = 0; h < 2; h++)
        #pragma unroll
        for (int j = 0; j < 2; j++) {
            int ra = mR + h * 128 + (wave * 2 + j) * 8 + rowLoc;
            if (ra > NPAD - 1) ra = NPAD - 1;   // clamp: garbage rows store-masked
            aSrcH[h][j] = Ag + (size_t)ra * NPAD + gOff;
            const int rb = nR + h * 128 + (wave * 2 + j) * 8 + rowLoc;
            bSrcH[h][j] = Bg + (size_t)rb * NPAD + gOff;
        }

    // per-thread bias values (col&31 = (nj&1)*16 + rRow)
    const float bias0 = bias[rRow];
    const float bias1 = bias[16 + rRow];

    floatx4 acc[8][4];
    const floatx4 zero4 = {0.f, 0.f, 0.f, 0.f};
    #pragma unroll
    for (int i = 0; i < 8; i++)
        #pragma unroll
        for (int j = 0; j < 4; j++) acc[i][j] = zero4;

    // ---- prologue: stage tile 0 (all 4 halves) ----
    STAGE_A(0, 0); STAGE_A(0, 1);
    STAGE_B(0, 0); STAGE_B(0, 1);

    #pragma unroll 2
    for (int t = 0; t < KT_G3; ++t) {
        // boundary: this tile's loads were issued a full tile ago
        asm volatile("s_waitcnt vmcnt(0)" ::: "memory");
        bar();

        const int sA = (2 * t + vm)  & 3;
        const int sB = (2 * t + hbB) & 3;
        const __hip_bfloat16* Ab = &Ah[sA][aRow0];
        const __hip_bfloat16* Bb = &Bh[sB][bRow0];

        bf16x8 a_[4], b_[4];

        // ---- p0: kh=0, mh=0 ----
        #pragma unroll
        for (int nj = 0; nj < 4; nj++) b_[nj] = *(const bf16x8*)(Bb + nj * 1024 + koff0);
        #pragma unroll
        for (int mi = 0; mi < 4; mi++) a_[mi] = *(const bf16x8*)(Ab + mi * 1024 + koff0);
        if (t + 1 < KT_G3) { STAGE_A(t + 1, 0); STAGE_A(t + 1, 1); }
        __builtin_amdgcn_s_setprio(1);
        #pragma unroll
        for (int mi = 0; mi < 4; mi++)
            #pragma unroll
            for (int nj = 0; nj < 4; nj++)
                acc[mi][nj] = __builtin_amdgcn_mfma_f32_16x16x32_bf16(a_[mi], b_[nj], acc[mi][nj], 0, 0, 0);
        __builtin_amdgcn_s_setprio(0);

        // ---- p1: kh=0, mh=1 (reuse b_ regs) ----
        #pragma unroll
        for (int mi = 0; mi < 4; mi++) a_[mi] = *(const bf16x8*)(Ab + (4 + mi) * 1024 + koff0);
        if (t + 1 < KT_G3) { STAGE_B(t + 1, 0); STAGE_B(t + 1, 1); }
        __builtin_amdgcn_s_setprio(1);
        #pragma unroll
        for (int mi = 0; mi < 4; mi++)
            #pragma unroll
            for (int nj = 0; nj < 4; nj++)
                acc[4 + mi][nj] = __builtin_amdgcn_mfma_f32_16x16x32_bf16(a_[mi], b_[nj], acc[4 + mi][nj], 0, 0, 0);
        __builtin_amdgcn_s_setprio(0);

        // ---- p2: kh=1, mh=0 ----
        #pragma unroll
        for (int nj = 0; nj < 4; nj++) b_[nj] = *(const bf16x8*)(Bb + nj * 1024 + koff1);
        #pragma unroll
        for (int mi = 0; mi < 4; mi++) a_[mi] = *(const bf16x8*)(Ab + mi * 1024 + koff1);
        __builtin_amdgcn_s_setprio(1);
        #pragma unroll
        for (int mi = 0; mi < 4; mi++)
            #pragma unroll
            for (int nj = 0; nj < 4; nj++)
                acc[mi][nj] = __builtin_amdgcn_mfma_f32_16x16x32_bf16(a_[mi], b_[nj], acc[mi][nj], 0, 0, 0);
        __builtin_amdgcn_s_setprio(0);

        // ---- p3: kh=1, mh=1 ----
        #pragma unroll
        for (int mi = 0; mi < 4; mi++) a_[mi] = *(const bf16x8*)(Ab + (4 + mi) * 1024 + koff1);
        __builtin_amdgcn_s_setprio(1);
        #pragma unroll
        for (int mi = 0; mi < 4; mi++)
            #pragma unroll
            for (int nj = 0; nj < 4; nj++)
                acc[4 + mi][nj] = __builtin_amdgcn_mfma_f32_16x16x32_bf16(a_[mi], b_[nj], acc[4 + mi][nj], 0, 0, 0);
        __builtin_amdgcn_s_setprio(0);
    }

    // ---- epilogue: C/D layout col=lane&15, row=(lane>>4)*4+reg (m89/m91) ----
    #pragma unroll
    for (int mi = 0; mi < 8; mi++) {
        #pragma unroll
        for (int nj = 0; nj < 4; nj++) {
            #pragma unroll
            for (int r = 0; r < 4; r++) {
                const int row = mR + vm * 128 + mi * 16 + gHi * 4 + r;
                if (row < NREAL) {
                    const int col = nR + vn * 64 + nj * 16 + rRow;
                    const int c = col & 31, b = col >> 5;
                    const float bv = (nj & 1) ? bias1 : bias0;
                    const float v = elu_f(acc[mi][nj][r] + bv);
                    outH[(size_t)b * KFC + row * 32 + c] = __float2bfloat16(v);
                }
            }
        }
    }
}

// ---------------------------------------------------------------------------
// Conversions / padding
// ---------------------------------------------------------------------------
__global__ void convX(const float* __restrict__ x, __hip_bfloat16* __restrict__ Xbf) {
    const int idx = blockIdx.x * 256 + threadIdx.x;
    if (idx >= BATCH * NPAD) return;
    const int m = idx % NPAD, b = idx / NPAD;
    const float v = (m < NREAL) ? x[(size_t)b * NREAL + m] : 0.f;
    Xbf[idx] = __float2bfloat16(v);
}

__global__ void convA(const float* __restrict__ a, __hip_bfloat16* __restrict__ Abf) {
    const int idx = blockIdx.x * 256 + threadIdx.x;
    if (idx >= NPAD * NPAD) return;
    const int m = idx % NPAD, n = idx / NPAD;
    const float v = (m < NREAL && n < NREAL) ? a[(size_t)n * NREAL + m] : 0.f;
    Abf[idx] = __float2bfloat16(v);
}

// wf1 [25088][512] fp32 -> Wt [512][25088] bf16 (LDS tile transpose)
__global__ void convW(const float* __restrict__ wf1, __hip_bfloat16* __restrict__ Wt) {
    __shared__ float tile[32][33];
    const int k0 = blockIdx.x * 32, h0 = blockIdx.y * 32;
    const int tx = threadIdx.x, ty = threadIdx.y;  // (32,8)
    #pragma unroll
    for (int i = 0; i < 4; i++)
        tile[ty * 4 + i][tx] = wf1[(size_t)(k0 + ty * 4 + i) * HDIM + h0 + tx];
    __syncthreads();
    #pragma unroll
    for (int i = 0; i < 4; i++)
        Wt[(size_t)(h0 + ty * 4 + i) * KFC + k0 + tx] = __float2bfloat16(tile[tx][ty * 4 + i]);
}

// ---------------------------------------------------------------------------
// Layer-1 fused pointwise
// ---------------------------------------------------------------------------
__global__ void layer1_fuse(const float* __restrict__ Ypart,
                            const float* __restrict__ w1, const float* __restrict__ b1,
                            const float* __restrict__ w2,
                            __hip_bfloat16* __restrict__ Tt)
{
    __shared__ __align__(16) float sW2[C1D * C2D];
    __shared__ float sw1[C1D], sb1[C1D];
    const int tid = threadIdx.x;                 // 128 threads
    for (int i = tid; i < C1D * C2D; i += 128) sW2[i] = w2[i];
    if (tid < C1D) { sw1[tid] = w1[tid]; sb1[tid] = b1[tid]; }
    __syncthreads();

    const int m = blockIdx.x * 128 + tid;        // 0..895
    const int b = blockIdx.y;
    float y = 0.f;
    #pragma unroll
    for (int z = 0; z < KS_G1; z++)
        y += Ypart[(size_t)z * (BATCH * NPAD) + (size_t)b * NPAD + m];

    float h[C1D];
    #pragma unroll
    for (int c1 = 0; c1 < C1D; c1++) h[c1] = elu_f(y * sw1[c1] + sb1[c1]);

    float4 t4[8];
    #pragma unroll
    for (int q = 0; q < 8; q++) t4[q] = make_float4(0.f, 0.f, 0.f, 0.f);
    #pragma unroll
    for (int c1 = 0; c1 < C1D; c1++) {
        const float hv = h[c1];
        const float4* row = (const float4*)(sW2 + c1 * C2D);
        #pragma unroll
        for (int q = 0; q < 8; q++) {
            const float4 w = row[q];
            t4[q].x += hv * w.x; t4[q].y += hv * w.y;
            t4[q].z += hv * w.z; t4[q].w += hv * w.w;
        }
    }
    const float* tf = (const float*)t4;
    #pragma unroll
    for (int c = 0; c < C2D; c++)
        Tt[((size_t)(b * 32 + c)) * NPAD + m] = __float2bfloat16(tf[c]);
}

// ---------------------------------------------------------------------------
// fc1 reduce + relu + fc2 + softmax, fused.
// ---------------------------------------------------------------------------
__global__ void fc2_softmax(const float* __restrict__ part, const float* __restrict__ bf1,
                            const float* __restrict__ wf2, const float* __restrict__ bf2,
                            float* __restrict__ out)
{
    __shared__ float sW[HDIM * NCLS];
    __shared__ float sb[NCLS];
    const int tid = threadIdx.x;                 // 256
    for (int i = tid; i < HDIM * NCLS; i += 256) sW[i] = wf2[i];
    if (tid < NCLS) sb[tid] = bf2[tid];
    __syncthreads();

    const int lane = tid & 63, wave = tid >> 6;
    const int b = blockIdx.x * 4 + wave;

    float acc[NCLS];
    #pragma unroll
    for (int c = 0; c < NCLS; c++) acc[c] = 0.f;
    #pragma unroll
    for (int q = 0; q < 8; q++) {
        const int h = q * 64 + lane;
        float hv = bf1[h];
        #pragma unroll
        for (int z = 0; z < KS_FC; z++)
            hv += part[(size_t)z * (BATCH * HDIM) + (size_t)b * HDIM + h];
        hv = hv > 0.f ? hv : 0.f;
        #pragma unroll
        for (int c = 0; c < NCLS; c++) acc[c] += hv * sW[h * NCLS + c];
    }
    #pragma unroll
    for (int c = 0; c < NCLS; c++) {
        #pragma unroll
        for (int off = 32; off >= 1; off >>= 1) acc[c] += __shfl_down(acc[c], off);
    }
    if (lane == 0) {
        float mx = -1e30f;
        #pragma unroll
        for (int c = 0; c < NCLS; c++) { acc[c] += sb[c]; mx = fmaxf(mx, acc[c]); }
        float e[NCLS], s = 0.f;
        #pragma unroll
        for (int c = 0; c < NCLS; c++) { e[c] = __expf(acc[c] - mx); s += e[c]; }
        const float inv = 1.f / s;
        #pragma unroll
        for (int c = 0; c < NCLS; c++) out[(size_t)b * NCLS + c] = e[c] * inv;
    }
}

// ---------------------------------------------------------------------------
// Workspace layout (peak ~113.5 MB) — unchanged
//   h2f   [0,          51380224)  bf16 1024x25088  (written G3, read G4)
//     Ypart [0, 25690112) f32 7x1024x896 — overlay, dead before G3 writes h2f
//   Tt    [51380224,  110100480)  bf16 32768x896   (dead after G3)
//     Wt   [51380224, 77070336)   bf16 512x25088 — overlay after G3
//     part [77070336, 106430464)  f32 14x1024x512 — overlay after G3
//   Abf   [110100480, 111706112)  bf16 896x896
//   Xbf   [111706112, 113541120)  bf16 1024x896    (dead after G1)
// ---------------------------------------------------------------------------
extern "C" void kernel_launch(void* const* d_in, const int* in_sizes, int n_in,
                              void* d_out, int out_size, void* d_ws, size_t ws_size,
                              hipStream_t stream)
{
    const float* x   = (const float*)d_in[0];
    const float* a   = (const float*)d_in[1];
    const float* w1  = (const float*)d_in[2];
    const float* b1  = (const float*)d_in[3];
    const float* w2  = (const float*)d_in[4];
    const float* b2  = (const float*)d_in[5];
    const float* wf1 = (const float*)d_in[6];
    const float* bf1 = (const float*)d_in[7];
    const float* wf2 = (const float*)d_in[8];
    const float* bf2 = (const float*)d_in[9];
    float* out = (float*)d_out;

    char* ws = (char*)d_ws;
    __hip_bfloat16* h2f  = (__hip_bfloat16*)(ws + 0);
    float*          Ypart= (float*)(ws + 0);                  // overlay (pre-G3)
    __hip_bfloat16* Tt   = (__hip_bfloat16*)(ws + 51380224);
    __hip_bfloat16* Wt   = (__hip_bfloat16*)(ws + 51380224);  // overlay (post-G3)
    float*          part = (float*)(ws + 77070336);           // overlay (post-G3)
    __hip_bfloat16* Abf  = (__hip_bfloat16*)(ws + 110100480);
    __hip_bfloat16* Xbf  = (__hip_bfloat16*)(ws + 111706112);

    convX<<<(BATCH * NPAD + 255) / 256, 256, 0, stream>>>(x, Xbf);
    convA<<<(NPAD * NPAD + 255) / 256, 256, 0, stream>>>(a, Abf);

    // G1: Ypart[z][b][n] partials of sum_m Xbf[b][m]*Abf[n][m]
    gemm_bt<2><<<dim3(NPAD / BN, BATCH / BM, KS_G1), 256, 0, stream>>>(
        Xbf, NPAD, Abf, NPAD, (NPAD / KS_G1) / BK, NPAD / KS_G1,
        (size_t)BATCH * NPAD, Ypart, NPAD, nullptr, nullptr);

    // layer-1 pointwise + @W2, transposed store
    layer1_fuse<<<dim3(NPAD / 128, BATCH), 128, 0, stream>>>(Ypart, w1, b1, w2, Tt);

    // G3: h2 = elu(A @ T + b2) — per-wave-owned-output 256^2 kernel
    gemm256_g3<<<dim3(BATCH * 32 / 256, 1024 / 256), 512, 0, stream>>>(Abf, Tt, h2f, b2);

    // transpose wf1 -> bf16 (into the now-dead Tt region)
    convW<<<dim3(KFC / 32, HDIM / 32), dim3(32, 8), 0, stream>>>(wf1, Wt);

    // G4: fc1 partials, split-K=14
    gemm_bt<2><<<dim3(HDIM / BN, BATCH / BM, KS_FC), 256, 0, stream>>>(
        h2f, KFC, Wt, KFC, (KFC / KS_FC) / BK, KFC / KS_FC,
        (size_t)BATCH * HDIM, part, HDIM, nullptr, nullptr);

    // fc1 reduce + relu + fc2 + softmax
    fc2_softmax<<<BATCH / 4, 256, 0, stream>>>(part, bf1, wf2, bf2, out);
}

// Round 4
// 273.306 us; speedup vs baseline: 1.0821x; 1.0821x over previous
//
#include <hip/hip_runtime.h>
#include <hip/hip_bf16.h>
#include <math.h>

// Problem constants
#define BATCH 1024
#define NREAL 784
#define NPAD  896      // 7*128, zero-padded graph dim
#define C1D   32
#define C2D   32
#define HDIM  512
#define NCLS  10
#define KFC   25088    // 784*32

#define KS_G1 7        // split-K for G1 (K=896 -> 128/slice, 4 iters, EVEN)
#define KS_FC 14       // split-K for fc1 (K=25088 -> 1792/slice, 56 iters, EVEN)

// GEMM tile (128x128 kernel, used for G1/G4)
#define BM 128
#define BN 128
#define BK 32

using bf16x8  = __attribute__((ext_vector_type(8))) __bf16;
using floatx4 = __attribute__((ext_vector_type(4))) float;

__device__ __forceinline__ float elu_f(float t) {
    return t > 0.f ? t : (__expf(t) - 1.f);
}

// LDS-only barrier: waits ds ops but leaves global loads (vmcnt) in flight.
__device__ __forceinline__ void wg_barrier_lds() {
    asm volatile("s_waitcnt lgkmcnt(0)\n\ts_barrier" ::: "memory");
}

// raw barrier (no waitcnt)
__device__ __forceinline__ void bar() {
    asm volatile("s_barrier" ::: "memory");
}

// async global->LDS, 16B per lane; LDS dest is wave-uniform base + lane*16
__device__ __forceinline__ void gload_lds16(const __hip_bfloat16* g, __hip_bfloat16* l) {
    __builtin_amdgcn_global_load_lds(
        (const __attribute__((address_space(1))) void*)g,
        (__attribute__((address_space(3))) void*)l, 16, 0, 0);
}

// ---------------------------------------------------------------------------
// BT-GEMM, register-staged pipeline + XOR-swizzled LDS layout (G1, G4).
// (unchanged)
// ---------------------------------------------------------------------------
template<int MODE>
__launch_bounds__(256)
__global__ void gemm_bt(const __hip_bfloat16* __restrict__ A, int lda,
                        const __hip_bfloat16* __restrict__ Bm, int ldb,
                        int kIters, int kPerZ, size_t sliceStride,
                        float* __restrict__ outF, int ldc,
                        __hip_bfloat16* __restrict__ outH,
                        const float* __restrict__ bias)
{
    __shared__ __align__(16) __hip_bfloat16 As[2][BM * BK];
    __shared__ __align__(16) __hip_bfloat16 Bs[2][BN * BK];

    const int tid  = threadIdx.x;
    const int lane = tid & 63;
    const int wave = tid >> 6;
    const int wi = wave >> 1, wj = wave & 1;

    const int m0 = blockIdx.y * BM;
    const int n0 = blockIdx.x * BN;
    const int kBase = blockIdx.z * kPerZ;

    const int rowInChunk = lane >> 2;
    const int kOff8 = (lane & 3) * 8;

    const __hip_bfloat16* aSrc0 = A  + (size_t)(m0 + (wave * 2 + 0) * 16 + rowInChunk) * lda + kBase + kOff8;
    const __hip_bfloat16* aSrc1 = A  + (size_t)(m0 + (wave * 2 + 1) * 16 + rowInChunk) * lda + kBase + kOff8;
    const __hip_bfloat16* bSrc0 = Bm + (size_t)(n0 + (wave * 2 + 0) * 16 + rowInChunk) * ldb + kBase + kOff8;
    const __hip_bfloat16* bSrc1 = Bm + (size_t)(n0 + (wave * 2 + 1) * 16 + rowInChunk) * ldb + kBase + kOff8;

    const int wSlot = (((lane & 3) + ((lane >> 3) & 3)) & 3) * 8;
    const int ldsW0 = (wave * 2 + 0) * 512 + rowInChunk * 32 + wSlot;
    const int ldsW1 = ldsW0 + 512;

    const int rSlot = ((((lane >> 4) + (((lane & 15) >> 1) & 3)) & 3)) * 8;
    const int rRow  = lane & 15;

    floatx4 acc[4][4];
    const floatx4 zero4 = {0.f, 0.f, 0.f, 0.f};
    #pragma unroll
    for (int i = 0; i < 4; i++)
        #pragma unroll
        for (int j = 0; j < 4; j++) acc[i][j] = zero4;

    int4 aA0, aA1, bA0, bA1;
    int4 aB0, aB1, bB0, bB1;

    aA0 = *(const int4*)aSrc0; aA1 = *(const int4*)aSrc1;
    bA0 = *(const int4*)bSrc0; bA1 = *(const int4*)bSrc1;
    aSrc0 += BK; aSrc1 += BK; bSrc0 += BK; bSrc1 += BK;
    aB0 = *(const int4*)aSrc0; aB1 = *(const int4*)aSrc1;
    bB0 = *(const int4*)bSrc0; bB1 = *(const int4*)bSrc1;
    aSrc0 += BK; aSrc1 += BK; bSrc0 += BK; bSrc1 += BK;

    *(int4*)(&As[0][ldsW0]) = aA0;
    *(int4*)(&As[0][ldsW1]) = aA1;
    *(int4*)(&Bs[0][ldsW0]) = bA0;
    *(int4*)(&Bs[0][ldsW1]) = bA1;
    wg_barrier_lds();

    for (int kt = 0; kt < kIters; kt += 2) {
        const bool more = (kt + 2 < kIters);

        {
            bf16x8 af[4], bfr[4];
            #pragma unroll
            for (int mi = 0; mi < 4; mi++)
                af[mi] = *(const bf16x8*)(&As[0][(wi * 64 + mi * 16 + rRow) * BK + rSlot]);
            #pragma unroll
            for (int nj = 0; nj < 4; nj++)
                bfr[nj] = *(const bf16x8*)(&Bs[0][(wj * 64 + nj * 16 + rRow) * BK + rSlot]);

            if (more) {
                aA0 = *(const int4*)aSrc0; aA1 = *(const int4*)aSrc1;
                bA0 = *(const int4*)bSrc0; bA1 = *(const int4*)bSrc1;
                aSrc0 += BK; aSrc1 += BK; bSrc0 += BK; bSrc1 += BK;
            }
            *(int4*)(&As[1][ldsW0]) = aB0;
            *(int4*)(&As[1][ldsW1]) = aB1;
            *(int4*)(&Bs[1][ldsW0]) = bB0;
            *(int4*)(&Bs[1][ldsW1]) = bB1;

            #pragma unroll
            for (int mi = 0; mi < 4; mi++)
                #pragma unroll
                for (int nj = 0; nj < 4; nj++)
                    acc[mi][nj] = __builtin_amdgcn_mfma_f32_16x16x32_bf16(af[mi], bfr[nj], acc[mi][nj], 0, 0, 0);

            wg_barrier_lds();
        }

        {
            bf16x8 af[4], bfr[4];
            #pragma unroll
            for (int mi = 0; mi < 4; mi++)
                af[mi] = *(const bf16x8*)(&As[1][(wi * 64 + mi * 16 + rRow) * BK + rSlot]);
            #pragma unroll
            for (int nj = 0; nj < 4; nj++)
                bfr[nj] = *(const bf16x8*)(&Bs[1][(wj * 64 + nj * 16 + rRow) * BK + rSlot]);

            if (more) {
                aB0 = *(const int4*)aSrc0; aB1 = *(const int4*)aSrc1;
                bB0 = *(const int4*)bSrc0; bB1 = *(const int4*)bSrc1;
                aSrc0 += BK; aSrc1 += BK; bSrc0 += BK; bSrc1 += BK;
                *(int4*)(&As[0][ldsW0]) = aA0;
                *(int4*)(&As[0][ldsW1]) = aA1;
                *(int4*)(&Bs[0][ldsW0]) = bA0;
                *(int4*)(&Bs[0][ldsW1]) = bA1;
            }

            #pragma unroll
            for (int mi = 0; mi < 4; mi++)
                #pragma unroll
                for (int nj = 0; nj < 4; nj++)
                    acc[mi][nj] = __builtin_amdgcn_mfma_f32_16x16x32_bf16(af[mi], bfr[nj], acc[mi][nj], 0, 0, 0);

            wg_barrier_lds();
        }
    }

    #pragma unroll
    for (int mi = 0; mi < 4; mi++) {
        #pragma unroll
        for (int nj = 0; nj < 4; nj++) {
            #pragma unroll
            for (int r = 0; r < 4; r++) {
                const int row = m0 + wi * 64 + mi * 16 + (lane >> 4) * 4 + r;
                const int col = n0 + wj * 64 + nj * 16 + (lane & 15);
                const float v = acc[mi][nj][r];
                if (MODE == 1) {
                    if (row < NREAL) {
                        const int c = col & 31, b = col >> 5;
                        const float t = elu_f(v + bias[c]);
                        outH[(size_t)b * KFC + row * 32 + c] = __float2bfloat16(t);
                    }
                } else {
                    outF[(size_t)blockIdx.z * sliceStride + (size_t)row * ldc + col] = v;
                }
            }
        }
    }
}

// ---------------------------------------------------------------------------
// G3: 256x256 quadrant-per-phase GEMM, half-slot ring + register frag reuse.
//
//   C[n][j] = sum_m Abf[n][m] * Tt[j][m].  K = 896 = 14 tiles of BK=64.
//
// 8 waves (vm=w>>2 in 0..1, vn=w&3).  Per phase ALL waves compute one
// 128x128 C-quadrant (QM,QN); wave's share = rows QM*128+vm*64+mi*16,
// cols QN*128+vn*32+nj*16 (16 MFMA).  Phase order (0,0),(0,1),(1,1),(1,0):
//   P1: read aF<-A0 (8), bF<-B0 (4);  P2: reuse aF, read bF<-B1 (4)
//   P3: read aF<-A1 (8), reuse bF(B1); P4: reuse aF, read bF<-B0 (4)
// 28 ds_read_b128/tile/wave (round 2: 48) with round-2-level live regs.
//
// LDS: ring of 4 half-slots/matrix, slot(t,h) = (2t+h)&3 (128 KiB).
// Rotation swizzle in rows; staging = linear LDS dest + pre-swizzled
// global source (rule #21).  STAGE_X(t,h) = 2 gloads/wave (all waves).
//
// Ledger (verified case-by-case):
//   retire:  A0(t),B0(t)* after t.P1-reads; B1(t) after t.P2; A1(t) after
//            t.P3; B0(t) re-read at t.P4 -> its slot live to boundary(t+1).
//   issue:   t.P1: {A1,B0}(t+1)  [into slots of A1,B0(t-1), retired]
//            t.P3: {A0,B1}(t+2)  [into slots of A0,B1(t), retired at mid]
//   leads:   A0: 6 phases, B1: 7, A1: 6, B0: 4.
//   wait:    ONE per tile: boundary vmcnt(4) (younger = {A0,B1}(t+1));
//            covers A0,B0,B1,A1(t) all at once ({A1,B0}(t) is older).
//            t=13: vmcnt(0).  No mid-tile vmcnt.
//   barriers: 2/tile (boundary, mid) — WAR fences for the issue points.
// ---------------------------------------------------------------------------
#define KT_G3 14

#define STAGE_A(tt, hh) do {                                                    \
    const int s_ = (2 * (tt) + (hh)) & 3;                                       \
    gload_lds16(aSrcH[hh][0] + (tt) * 64, &Ah[s_][(wave * 2 + 0) * 512]);       \
    gload_lds16(aSrcH[hh][1] + (tt) * 64, &Ah[s_][(wave * 2 + 1) * 512]);       \
} while (0)

#define STAGE_B(tt, hh) do {                                                    \
    const int s_ = (2 * (tt) + (hh)) & 3;                                       \
    gload_lds16(bSrcH[hh][0] + (tt) * 64, &Bh[s_][(wave * 2 + 0) * 512]);       \
    gload_lds16(bSrcH[hh][1] + (tt) * 64, &Bh[s_][(wave * 2 + 1) * 512]);       \
} while (0)

__launch_bounds__(512, 2)
__global__ void gemm256_g3(const __hip_bfloat16* __restrict__ Ag,   // Abf [896][896]
                           const __hip_bfloat16* __restrict__ Bg,   // Tt  [32768][896]
                           __hip_bfloat16* __restrict__ outH,       // h2f
                           const float* __restrict__ bias)          // b2 [32]
{
    __shared__ __align__(16) __hip_bfloat16 Ah[4][128 * 64];
    __shared__ __align__(16) __hip_bfloat16 Bh[4][128 * 64];

    const int tid  = threadIdx.x;
    const int lane = tid & 63;
    const int wave = tid >> 6;
    const int vm = wave >> 2, vn = wave & 3;

    const int mR = blockIdx.y * 256;    // output rows (Abf rows; >=896 clamped+masked)
    const int nR = blockIdx.x * 256;    // output cols (Tt rows)

    // ---- read-side constants ----
    const int rRow = lane & 15;
    const int gHi  = lane >> 4;              // 0..3 (k-group within half-K)
    const int rot  = lane & 7;               // == (read row) & 7
    const int koff0 = (((gHi + rot) & 7) << 3);
    const int koff1 = ((((gHi + 4) + rot) & 7) << 3);
    const int aBase = (vm * 64 + rRow) * 64;   // + mi*1024, within a 128-row A-half
    const int bBase = (vn * 32 + rRow) * 64;   // + nj*1024, within a 128-row B-half

    // ---- staging constants (pre-swizzled global source, linear LDS dest) ----
    const int rowLoc = lane >> 3;                       // row within 8-row chunk
    const int gOff   = ((((lane & 7) - rowLoc) & 7) << 3);
    const __hip_bfloat16* aSrcH[2][2];
    const __hip_bfloat16* bSrcH[2][2];
    #pragma unroll
    for (int h = 0; h < 2; h++)
        #pragma unroll
        for (int j = 0; j < 2; j++) {
            int ra = mR + h * 128 + (wave * 2 + j) * 8 + rowLoc;
            if (ra > NPAD - 1) ra = NPAD - 1;   // clamp: garbage rows store-masked
            aSrcH[h][j] = Ag + (size_t)ra * NPAD + gOff;
            const int rb = nR + h * 128 + (wave * 2 + j) * 8 + rowLoc;
            bSrcH[h][j] = Bg + (size_t)rb * NPAD + gOff;
        }

    // per-thread bias values (col&31 = nj*16 + rRow)
    const float bias0 = bias[rRow];
    const float bias1 = bias[16 + rRow];

    floatx4 acc[4][4][2];      // [QM*2+QN][mi][nj]
    const floatx4 zero4 = {0.f, 0.f, 0.f, 0.f};
    #pragma unroll
    for (int q = 0; q < 4; q++)
        #pragma unroll
        for (int i = 0; i < 4; i++)
            #pragma unroll
            for (int j = 0; j < 2; j++) acc[q][i][j] = zero4;

    // ---- prologue (ledger order): {A0,B1}(0), {A1,B0}(0), {A0,B1}(1) ----
    STAGE_A(0, 0); STAGE_B(0, 1);
    STAGE_A(0, 1); STAGE_B(0, 0);
    STAGE_A(1, 0); STAGE_B(1, 1);

    #pragma unroll 2
    for (int t = 0; t < KT_G3; ++t) {
        // ---- boundary: single counted wait covers all 4 halves of tile t ----
        if (t + 1 < KT_G3) { asm volatile("s_waitcnt vmcnt(4)" ::: "memory"); }
        else               { asm volatile("s_waitcnt vmcnt(0)" ::: "memory"); }
        bar();

        const int sA0 = (2 * t + 0) & 3, sA1 = (2 * t + 1) & 3;
        const int sB0 = (2 * t + 0) & 3, sB1 = (2 * t + 1) & 3;

        bf16x8 aF[4][2], bF[2][2];

        // ---- P1: quadrant (0,0) — read aF<-A0, bF<-B0 ----
        #pragma unroll
        for (int mi = 0; mi < 4; mi++) {
            aF[mi][0] = *(const bf16x8*)(&Ah[sA0][aBase + mi * 1024 + koff0]);
            aF[mi][1] = *(const bf16x8*)(&Ah[sA0][aBase + mi * 1024 + koff1]);
        }
        #pragma unroll
        for (int nj = 0; nj < 2; nj++) {
            bF[nj][0] = *(const bf16x8*)(&Bh[sB0][bBase + nj * 1024 + koff0]);
            bF[nj][1] = *(const bf16x8*)(&Bh[sB0][bBase + nj * 1024 + koff1]);
        }
        if (t + 1 < KT_G3) { STAGE_A(t + 1, 1); STAGE_B(t + 1, 0); }
        __builtin_amdgcn_s_setprio(1);
        #pragma unroll
        for (int mi = 0; mi < 4; mi++)
            #pragma unroll
            for (int nj = 0; nj < 2; nj++)
                acc[0][mi][nj] = __builtin_amdgcn_mfma_f32_16x16x32_bf16(aF[mi][0], bF[nj][0], acc[0][mi][nj], 0, 0, 0);
        #pragma unroll
        for (int mi = 0; mi < 4; mi++)
            #pragma unroll
            for (int nj = 0; nj < 2; nj++)
                acc[0][mi][nj] = __builtin_amdgcn_mfma_f32_16x16x32_bf16(aF[mi][1], bF[nj][1], acc[0][mi][nj], 0, 0, 0);
        __builtin_amdgcn_s_setprio(0);

        // ---- P2: quadrant (0,1) — reuse aF(A0), read bF<-B1 ----
        #pragma unroll
        for (int nj = 0; nj < 2; nj++) {
            bF[nj][0] = *(const bf16x8*)(&Bh[sB1][bBase + nj * 1024 + koff0]);
            bF[nj][1] = *(const bf16x8*)(&Bh[sB1][bBase + nj * 1024 + koff1]);
        }
        __builtin_amdgcn_s_setprio(1);
        #pragma unroll
        for (int mi = 0; mi < 4; mi++)
            #pragma unroll
            for (int nj = 0; nj < 2; nj++)
                acc[1][mi][nj] = __builtin_amdgcn_mfma_f32_16x16x32_bf16(aF[mi][0], bF[nj][0], acc[1][mi][nj], 0, 0, 0);
        #pragma unroll
        for (int mi = 0; mi < 4; mi++)
            #pragma unroll
            for (int nj = 0; nj < 2; nj++)
                acc[1][mi][nj] = __builtin_amdgcn_mfma_f32_16x16x32_bf16(aF[mi][1], bF[nj][1], acc[1][mi][nj], 0, 0, 0);
        __builtin_amdgcn_s_setprio(0);

        // ---- mid barrier: A0(t),B1(t) reads complete everywhere (WAR fence) ----
        bar();

        // ---- P3: quadrant (1,1) — read aF<-A1, reuse bF(B1) ----
        #pragma unroll
        for (int mi = 0; mi < 4; mi++) {
            aF[mi][0] = *(const bf16x8*)(&Ah[sA1][aBase + mi * 1024 + koff0]);
            aF[mi][1] = *(const bf16x8*)(&Ah[sA1][aBase + mi * 1024 + koff1]);
        }
        if (t + 2 < KT_G3) { STAGE_A(t + 2, 0); STAGE_B(t + 2, 1); }
        __builtin_amdgcn_s_setprio(1);
        #pragma unroll
        for (int mi = 0; mi < 4; mi++)
            #pragma unroll
            for (int nj = 0; nj < 2; nj++)
                acc[3][mi][nj] = __builtin_amdgcn_mfma_f32_16x16x32_bf16(aF[mi][0], bF[nj][0], acc[3][mi][nj], 0, 0, 0);
        #pragma unroll
        for (int mi = 0; mi < 4; mi++)
            #pragma unroll
            for (int nj = 0; nj < 2; nj++)
                acc[3][mi][nj] = __builtin_amdgcn_mfma_f32_16x16x32_bf16(aF[mi][1], bF[nj][1], acc[3][mi][nj], 0, 0, 0);
        __builtin_amdgcn_s_setprio(0);

        // ---- P4: quadrant (1,0) — reuse aF(A1), read bF<-B0 ----
        #pragma unroll
        for (int nj = 0; nj < 2; nj++) {
            bF[nj][0] = *(const bf16x8*)(&Bh[sB0][bBase + nj * 1024 + koff0]);
            bF[nj][1] = *(const bf16x8*)(&Bh[sB0][bBase + nj * 1024 + koff1]);
        }
        __builtin_amdgcn_s_setprio(1);
        #pragma unroll
        for (int mi = 0; mi < 4; mi++)
            #pragma unroll
            for (int nj = 0; nj < 2; nj++)
                acc[2][mi][nj] = __builtin_amdgcn_mfma_f32_16x16x32_bf16(aF[mi][0], bF[nj][0], acc[2][mi][nj], 0, 0, 0);
        #pragma unroll
        for (int mi = 0; mi < 4; mi++)
            #pragma unroll
            for (int nj = 0; nj < 2; nj++)
                acc[2][mi][nj] = __builtin_amdgcn_mfma_f32_16x16x32_bf16(aF[mi][1], bF[nj][1], acc[2][mi][nj], 0, 0, 0);
        __builtin_amdgcn_s_setprio(0);
    }

    // ---- epilogue: C/D layout col=lane&15, row=(lane>>4)*4+reg (m89/m91) ----
    #pragma unroll
    for (int q = 0; q < 4; q++) {
        const int qm = q >> 1, qn = q & 1;
        #pragma unroll
        for (int mi = 0; mi < 4; mi++) {
            #pragma unroll
            for (int nj = 0; nj < 2; nj++) {
                #pragma unroll
                for (int r = 0; r < 4; r++) {
                    const int row = mR + qm * 128 + vm * 64 + mi * 16 + gHi * 4 + r;
                    if (row < NREAL) {
                        const int col = nR + qn * 128 + vn * 32 + nj * 16 + rRow;
                        const int c = col & 31, b = col >> 5;
                        const float bv = nj ? bias1 : bias0;
                        const float v = elu_f(acc[q][mi][nj][r] + bv);
                        outH[(size_t)b * KFC + row * 32 + c] = __float2bfloat16(v);
                    }
                }
            }
        }
    }
}

// ---------------------------------------------------------------------------
// Conversions / padding
// ---------------------------------------------------------------------------
__global__ void convX(const float* __restrict__ x, __hip_bfloat16* __restrict__ Xbf) {
    const int idx = blockIdx.x * 256 + threadIdx.x;
    if (idx >= BATCH * NPAD) return;
    const int m = idx % NPAD, b = idx / NPAD;
    const float v = (m < NREAL) ? x[(size_t)b * NREAL + m] : 0.f;
    Xbf[idx] = __float2bfloat16(v);
}

__global__ void convA(const float* __restrict__ a, __hip_bfloat16* __restrict__ Abf) {
    const int idx = blockIdx.x * 256 + threadIdx.x;
    if (idx >= NPAD * NPAD) return;
    const int m = idx % NPAD, n = idx / NPAD;
    const float v = (m < NREAL && n < NREAL) ? a[(size_t)n * NREAL + m] : 0.f;
    Abf[idx] = __float2bfloat16(v);
}

// wf1 [25088][512] fp32 -> Wt [512][25088] bf16 (LDS tile transpose)
__global__ void convW(const float* __restrict__ wf1, __hip_bfloat16* __restrict__ Wt) {
    __shared__ float tile[32][33];
    const int k0 = blockIdx.x * 32, h0 = blockIdx.y * 32;
    const int tx = threadIdx.x, ty = threadIdx.y;  // (32,8)
    #pragma unroll
    for (int i = 0; i < 4; i++)
        tile[ty * 4 + i][tx] = wf1[(size_t)(k0 + ty * 4 + i) * HDIM + h0 + tx];
    __syncthreads();
    #pragma unroll
    for (int i = 0; i < 4; i++)
        Wt[(size_t)(h0 + ty * 4 + i) * KFC + k0 + tx] = __float2bfloat16(tile[tx][ty * 4 + i]);
}

// ---------------------------------------------------------------------------
// Layer-1 fused pointwise
// ---------------------------------------------------------------------------
__global__ void layer1_fuse(const float* __restrict__ Ypart,
                            const float* __restrict__ w1, const float* __restrict__ b1,
                            const float* __restrict__ w2,
                            __hip_bfloat16* __restrict__ Tt)
{
    __shared__ __align__(16) float sW2[C1D * C2D];
    __shared__ float sw1[C1D], sb1[C1D];
    const int tid = threadIdx.x;                 // 128 threads
    for (int i = tid; i < C1D * C2D; i += 128) sW2[i] = w2[i];
    if (tid < C1D) { sw1[tid] = w1[tid]; sb1[tid] = b1[tid]; }
    __syncthreads();

    const int m = blockIdx.x * 128 + tid;        // 0..895
    const int b = blockIdx.y;
    float y = 0.f;
    #pragma unroll
    for (int z = 0; z < KS_G1; z++)
        y += Ypart[(size_t)z * (BATCH * NPAD) + (size_t)b * NPAD + m];

    float h[C1D];
    #pragma unroll
    for (int c1 = 0; c1 < C1D; c1++) h[c1] = elu_f(y * sw1[c1] + sb1[c1]);

    float4 t4[8];
    #pragma unroll
    for (int q = 0; q < 8; q++) t4[q] = make_float4(0.f, 0.f, 0.f, 0.f);
    #pragma unroll
    for (int c1 = 0; c1 < C1D; c1++) {
        const float hv = h[c1];
        const float4* row = (const float4*)(sW2 + c1 * C2D);
        #pragma unroll
        for (int q = 0; q < 8; q++) {
            const float4 w = row[q];
            t4[q].x += hv * w.x; t4[q].y += hv * w.y;
            t4[q].z += hv * w.z; t4[q].w += hv * w.w;
        }
    }
    const float* tf = (const float*)t4;
    #pragma unroll
    for (int c = 0; c < C2D; c++)
        Tt[((size_t)(b * 32 + c)) * NPAD + m] = __float2bfloat16(tf[c]);
}

// ---------------------------------------------------------------------------
// fc1 reduce + relu + fc2 + softmax, fused.
// ---------------------------------------------------------------------------
__global__ void fc2_softmax(const float* __restrict__ part, const float* __restrict__ bf1,
                            const float* __restrict__ wf2, const float* __restrict__ bf2,
                            float* __restrict__ out)
{
    __shared__ float sW[HDIM * NCLS];
    __shared__ float sb[NCLS];
    const int tid = threadIdx.x;                 // 256
    for (int i = tid; i < HDIM * NCLS; i += 256) sW[i] = wf2[i];
    if (tid < NCLS) sb[tid] = bf2[tid];
    __syncthreads();

    const int lane = tid & 63, wave = tid >> 6;
    const int b = blockIdx.x * 4 + wave;

    float acc[NCLS];
    #pragma unroll
    for (int c = 0; c < NCLS; c++) acc[c] = 0.f;
    #pragma unroll
    for (int q = 0; q < 8; q++) {
        const int h = q * 64 + lane;
        float hv = bf1[h];
        #pragma unroll
        for (int z = 0; z < KS_FC; z++)
            hv += part[(size_t)z * (BATCH * HDIM) + (size_t)b * HDIM + h];
        hv = hv > 0.f ? hv : 0.f;
        #pragma unroll
        for (int c = 0; c < NCLS; c++) acc[c] += hv * sW[h * NCLS + c];
    }
    #pragma unroll
    for (int c = 0; c < NCLS; c++) {
        #pragma unroll
        for (int off = 32; off >= 1; off >>= 1) acc[c] += __shfl_down(acc[c], off);
    }
    if (lane == 0) {
        float mx = -1e30f;
        #pragma unroll
        for (int c = 0; c < NCLS; c++) { acc[c] += sb[c]; mx = fmaxf(mx, acc[c]); }
        float e[NCLS], s = 0.f;
        #pragma unroll
        for (int c = 0; c < NCLS; c++) { e[c] = __expf(acc[c] - mx); s += e[c]; }
        const float inv = 1.f / s;
        #pragma unroll
        for (int c = 0; c < NCLS; c++) out[(size_t)b * NCLS + c] = e[c] * inv;
    }
}

// ---------------------------------------------------------------------------
// Workspace layout (peak ~113.5 MB) — unchanged
//   h2f   [0,          51380224)  bf16 1024x25088  (written G3, read G4)
//     Ypart [0, 25690112) f32 7x1024x896 — overlay, dead before G3 writes h2f
//   Tt    [51380224,  110100480)  bf16 32768x896   (dead after G3)
//     Wt   [51380224, 77070336)   bf16 512x25088 — overlay after G3
//     part [77070336, 106430464)  f32 14x1024x512 — overlay after G3
//   Abf   [110100480, 111706112)  bf16 896x896
//   Xbf   [111706112, 113541120)  bf16 1024x896    (dead after G1)
// ---------------------------------------------------------------------------
extern "C" void kernel_launch(void* const* d_in, const int* in_sizes, int n_in,
                              void* d_out, int out_size, void* d_ws, size_t ws_size,
                              hipStream_t stream)
{
    const float* x   = (const float*)d_in[0];
    const float* a   = (const float*)d_in[1];
    const float* w1  = (const float*)d_in[2];
    const float* b1  = (const float*)d_in[3];
    const float* w2  = (const float*)d_in[4];
    const float* b2  = (const float*)d_in[5];
    const float* wf1 = (const float*)d_in[6];
    const float* bf1 = (const float*)d_in[7];
    const float* wf2 = (const float*)d_in[8];
    const float* bf2 = (const float*)d_in[9];
    float* out = (float*)d_out;

    char* ws = (char*)d_ws;
    __hip_bfloat16* h2f  = (__hip_bfloat16*)(ws + 0);
    float*          Ypart= (float*)(ws + 0);                  // overlay (pre-G3)
    __hip_bfloat16* Tt   = (__hip_bfloat16*)(ws + 51380224);
    __hip_bfloat16* Wt   = (__hip_bfloat16*)(ws + 51380224);  // overlay (post-G3)
    float*          part = (float*)(ws + 77070336);           // overlay (post-G3)
    __hip_bfloat16* Abf  = (__hip_bfloat16*)(ws + 110100480);
    __hip_bfloat16* Xbf  = (__hip_bfloat16*)(ws + 111706112);

    convX<<<(BATCH * NPAD + 255) / 256, 256, 0, stream>>>(x, Xbf);
    convA<<<(NPAD * NPAD + 255) / 256, 256, 0, stream>>>(a, Abf);

    // G1: Ypart[z][b][n] partials of sum_m Xbf[b][m]*Abf[n][m]
    gemm_bt<2><<<dim3(NPAD / BN, BATCH / BM, KS_G1), 256, 0, stream>>>(
        Xbf, NPAD, Abf, NPAD, (NPAD / KS_G1) / BK, NPAD / KS_G1,
        (size_t)BATCH * NPAD, Ypart, NPAD, nullptr, nullptr);

    // layer-1 pointwise + @W2, transposed store
    layer1_fuse<<<dim3(NPAD / 128, BATCH), 128, 0, stream>>>(Ypart, w1, b1, w2, Tt);

    // G3: h2 = elu(A @ T + b2) — quadrant-per-phase + frag-reuse 256^2 kernel
    gemm256_g3<<<dim3(BATCH * 32 / 256, 1024 / 256), 512, 0, stream>>>(Abf, Tt, h2f, b2);

    // transpose wf1 -> bf16 (into the now-dead Tt region)
    convW<<<dim3(KFC / 32, HDIM / 32), dim3(32, 8), 0, stream>>>(wf1, Wt);

    // G4: fc1 partials, split-K=14
    gemm_bt<2><<<dim3(HDIM / BN, BATCH / BM, KS_FC), 256, 0, stream>>>(
        h2f, KFC, Wt, KFC, (KFC / KS_FC) / BK, KFC / KS_FC,
        (size_t)BATCH * HDIM, part, HDIM, nullptr, nullptr);

    // fc1 reduce + relu + fc2 + softmax
    fc2_softmax<<<BATCH / 4, 256, 0, stream>>>(part, bf1, wf2, bf2, out);
}